// Round 4
// baseline (578.595 us; speedup 1.0000x reference)
//
#include <hip/hip_runtime.h>
#include <hip/hip_bf16.h>

// Problem constants (from reference)
#define DIMX   768
#define HEADS  12
#define DH     64
#define INNER  768
#define NQKV   2304
#define SEQ    4096
#define BATCH  2
#define ROWS   (BATCH*SEQ)   // 8192
#define EPSF   1e-8f
#define LOG2E  1.4426950408889634f

typedef __bf16 bf16x8 __attribute__((ext_vector_type(8)));
typedef float  f32x4  __attribute__((ext_vector_type(4)));
typedef float  f32x16 __attribute__((ext_vector_type(16)));

// RNE f32 -> bf16 (finite inputs only)
__device__ __forceinline__ unsigned short f2bf(float f) {
    unsigned int u = __float_as_uint(f);
    unsigned int r = ((u >> 16) & 1u) + 0x7FFFu;
    return (unsigned short)((u + r) >> 16);
}
__device__ __forceinline__ float bf2f(unsigned short u) {
    return __builtin_bit_cast(float, (unsigned)u << 16);
}
// pack two f32 into a u32 of 2 bf16 (lo = a, hi = b) via native casts
__device__ __forceinline__ unsigned pkbf(float a, float b) {
    unsigned short la = __builtin_bit_cast(unsigned short, (__bf16)a);
    unsigned short lb = __builtin_bit_cast(unsigned short, (__bf16)b);
    return (unsigned)la | ((unsigned)lb << 16);
}

__global__ __launch_bounds__(256) void cast_f32_bf16(
    const float* __restrict__ src, unsigned short* __restrict__ dst, int n)
{
    int i = (blockIdx.x * 256 + threadIdx.x) * 4;
    if (i + 3 < n) {
        float4 v = *reinterpret_cast<const float4*>(src + i);
        ushort4 o;
        o.x = f2bf(v.x); o.y = f2bf(v.y); o.z = f2bf(v.z); o.w = f2bf(v.w);
        *reinterpret_cast<ushort4*>(dst + i) = o;
    }
}

// C[M][N] = A[M][K] (bf16) * B[N][K]^T (bf16) (+ bias); out f32 or bf16.
template<bool BF16OUT>
__global__ __launch_bounds__(256) void gemm_bt_kernel(
    const unsigned short* __restrict__ A,
    const unsigned short* __restrict__ B,
    void* __restrict__ Cv,
    const float* __restrict__ bias,
    int M, int N, int K)
{
    __shared__ unsigned short shA[128][72];
    __shared__ unsigned short shB[128][72];

    const int bm0 = blockIdx.x * 128;
    const int bn0 = blockIdx.y * 128;
    const int tid = threadIdx.x;
    const int lane = tid & 63;
    const int wid  = tid >> 6;
    const int l15  = lane & 15;
    const int l4   = lane >> 4;
    const int wr   = wid >> 1;
    const int wc   = wid & 1;

    f32x4 acc[4][4];
    #pragma unroll
    for (int i = 0; i < 4; ++i)
        #pragma unroll
        for (int j = 0; j < 4; ++j)
            acc[i][j] = (f32x4){0.f, 0.f, 0.f, 0.f};

    const int nkt = K >> 6;
    for (int kt = 0; kt < nkt; ++kt) {
        const int k0 = kt << 6;
        __syncthreads();
        #pragma unroll
        for (int it = 0; it < 4; ++it) {
            int c = tid + it * 256;
            int row = c >> 3, colc = c & 7;
            *reinterpret_cast<uint4*>(&shA[row][colc * 8]) =
                *reinterpret_cast<const uint4*>(&A[(size_t)(bm0 + row) * K + k0 + colc * 8]);
            *reinterpret_cast<uint4*>(&shB[row][colc * 8]) =
                *reinterpret_cast<const uint4*>(&B[(size_t)(bn0 + row) * K + k0 + colc * 8]);
        }
        __syncthreads();
        #pragma unroll
        for (int ks = 0; ks < 2; ++ks) {
            bf16x8 af[4], bfr[4];
            #pragma unroll
            for (int mf = 0; mf < 4; ++mf)
                af[mf] = *reinterpret_cast<const bf16x8*>(&shA[wr * 64 + mf * 16 + l15][ks * 32 + l4 * 8]);
            #pragma unroll
            for (int nf = 0; nf < 4; ++nf)
                bfr[nf] = *reinterpret_cast<const bf16x8*>(&shB[wc * 64 + nf * 16 + l15][ks * 32 + l4 * 8]);
            #pragma unroll
            for (int mf = 0; mf < 4; ++mf)
                #pragma unroll
                for (int nf = 0; nf < 4; ++nf)
                    acc[mf][nf] = __builtin_amdgcn_mfma_f32_16x16x32_bf16(
                        af[mf], bfr[nf], acc[mf][nf], 0, 0, 0);
        }
    }

    #pragma unroll
    for (int mf = 0; mf < 4; ++mf) {
        #pragma unroll
        for (int nf = 0; nf < 4; ++nf) {
            int col = bn0 + wc * 64 + nf * 16 + l15;
            float badd = bias ? bias[col] : 0.f;
            #pragma unroll
            for (int r = 0; r < 4; ++r) {
                int row = bm0 + wr * 64 + mf * 16 + l4 * 4 + r;
                if constexpr (BF16OUT)
                    ((unsigned short*)Cv)[(size_t)row * N + col] = f2bf(acc[mf][nf][r] + badd);
                else
                    ((float*)Cv)[(size_t)row * N + col] = acc[mf][nf][r] + badd;
            }
        }
    }
}

// Cross-head L2 norm on bf16 qkv; Q scaled by log2e/scale[h]. q,k only.
__global__ __launch_bounds__(256) void normalize_kernel(
    const unsigned short* __restrict__ qkv,
    const float* __restrict__ scale,
    unsigned short* __restrict__ qo,
    unsigned short* __restrict__ ko)
{
    int t = blockIdx.x * 256 + threadIdx.x;
    int row = t >> 6;
    int d = t & 63;
    int b = row >> 12;
    int n = row & 4095;
    const unsigned short* base = qkv + (size_t)row * NQKV;

    float qv[12], kv[12];
    float sq = 0.f, sk = 0.f;
    #pragma unroll
    for (int h = 0; h < 12; ++h) {
        qv[h] = bf2f(base[h * 64 + d]);
        kv[h] = bf2f(base[768 + h * 64 + d]);
        sq += qv[h] * qv[h];
        sk += kv[h] * kv[h];
    }
    float rq = rsqrtf(sqrtf(sq) + EPSF);
    float rk = rsqrtf(sqrtf(sk) + EPSF);
    #pragma unroll
    for (int h = 0; h < 12; ++h) {
        size_t bh = (size_t)(b * 12 + h);
        float fold = LOG2E / scale[h];
        qo[(bh * SEQ + n) * 64 + d] = f2bf(qv[h] * rq * fold);
        ko[(bh * SEQ + n) * 64 + d] = f2bf(kv[h] * rk);
    }
}

// V transpose: qkv bf16 v-part [b,n,h,d] -> vt [bh][d][n], coalesced both ways
// via a 64x64 LDS tile. Grid: (BATCH*HEADS, SEQ/64).
__global__ __launch_bounds__(256) void vtrans_kernel(
    const unsigned short* __restrict__ qkv,
    unsigned short* __restrict__ vt)
{
    __shared__ unsigned short tile[64][72];
    const int bh = blockIdx.x;
    const int nt = blockIdx.y;
    const int b = bh / HEADS, h = bh % HEADS;
    const int tid = threadIdx.x;

    #pragma unroll
    for (int it = 0; it < 2; ++it) {
        int c = tid + it * 256;
        int r = c >> 3, cc = c & 7;
        *reinterpret_cast<uint4*>(&tile[r][cc * 8]) =
            *reinterpret_cast<const uint4*>(
                &qkv[(size_t)(b * SEQ + nt * 64 + r) * NQKV + 1536 + h * 64 + cc * 8]);
    }
    __syncthreads();
    #pragma unroll
    for (int it = 0; it < 2; ++it) {
        int c = tid + it * 256;
        int d = c >> 3, nc = c & 7;
        ushort4 o0, o1;
        o0.x = tile[nc * 8 + 0][d]; o0.y = tile[nc * 8 + 1][d];
        o0.z = tile[nc * 8 + 2][d]; o0.w = tile[nc * 8 + 3][d];
        o1.x = tile[nc * 8 + 4][d]; o1.y = tile[nc * 8 + 5][d];
        o1.z = tile[nc * 8 + 6][d]; o1.w = tile[nc * 8 + 7][d];
        unsigned short* dst = &vt[((size_t)bh * 64 + d) * SEQ + nt * 64 + nc * 8];
        *reinterpret_cast<ushort4*>(dst)     = o0;
        *reinterpret_cast<ushort4*>(dst + 4) = o1;
    }
}

// Flash attention, 8 waves / 512 threads. Waves 0-3: kv [0,2048); waves 4-7:
// kv [2048,4096); same 128 q-rows. End-of-kernel (m,l,O^T) combine via LDS.
struct ShExch { float ob[4][32][64]; float ml[4][64][2]; };
struct ShKV   { unsigned short K[2][64][72]; unsigned short V[2][64][72]; };
union  ShU    { ShKV kv; ShExch ex; };

__global__ __launch_bounds__(512, 6) void attn_kernel(
    const unsigned short* __restrict__ qg,
    const unsigned short* __restrict__ kg,
    const unsigned short* __restrict__ vtg,
    unsigned short* __restrict__ attnout)
{
    __shared__ ShU u;

    const int qblk = blockIdx.x;
    const int bh   = blockIdx.y;
    const int b    = bh / HEADS;
    const int h    = bh % HEADS;
    const int tid  = threadIdx.x;
    const int lane = tid & 63;
    const int wid  = tid >> 6;     // 0..7
    const int w    = wid & 3;      // q-subtile
    const int g    = wid >> 2;     // kv half
    const int l31  = lane & 31;
    const int hi   = lane >> 5;
    const int tidg = tid & 255;

    // Q fragments (B operand, col=q=l31, k = d0*16 + hi*8 + j)
    bf16x8 qf[4];
    {
        const unsigned short* qrow =
            qg + ((size_t)bh * SEQ + qblk * 128 + w * 32 + l31) * 64 + hi * 8;
        #pragma unroll
        for (int d0 = 0; d0 < 4; ++d0)
            qf[d0] = *reinterpret_cast<const bf16x8*>(qrow + d0 * 16);
    }

    f32x16 ot[2];
    #pragma unroll
    for (int r = 0; r < 16; ++r) { ot[0][r] = 0.f; ot[1][r] = 0.f; }
    float m_st = -1e30f, l_st = 0.f;

    const unsigned short* kbase = kg  + ((size_t)bh * SEQ + g * 2048) * 64;
    const unsigned short* vbase = vtg + (size_t)bh * 64 * SEQ + g * 2048;

    for (int kt = 0; kt < 32; ++kt) {
        __syncthreads();
        #pragma unroll
        for (int it = 0; it < 2; ++it) {
            int c = tidg + it * 256;
            int row = c >> 3, colc = c & 7;
            *reinterpret_cast<uint4*>(&u.kv.K[g][row][colc * 8]) =
                *reinterpret_cast<const uint4*>(&kbase[(size_t)(kt * 64 + row) * 64 + colc * 8]);
            *reinterpret_cast<uint4*>(&u.kv.V[g][row][colc * 8]) =
                *reinterpret_cast<const uint4*>(&vbase[(size_t)row * SEQ + kt * 64 + colc * 8]);
        }
        __syncthreads();

        // ---- S^T = K * Q^T (exp2 domain: scale folded into Q) ----
        f32x16 st0, st1;
        #pragma unroll
        for (int r = 0; r < 16; ++r) { st0[r] = 0.f; st1[r] = 0.f; }
        #pragma unroll
        for (int d0 = 0; d0 < 4; ++d0) {
            bf16x8 kf0 = *reinterpret_cast<const bf16x8*>(&u.kv.K[g][l31][d0 * 16 + hi * 8]);
            bf16x8 kf1 = *reinterpret_cast<const bf16x8*>(&u.kv.K[g][32 + l31][d0 * 16 + hi * 8]);
            st0 = __builtin_amdgcn_mfma_f32_32x32x16_bf16(kf0, qf[d0], st0, 0, 0, 0);
            st1 = __builtin_amdgcn_mfma_f32_32x32x16_bf16(kf1, qf[d0], st1, 0, 0, 0);
        }

        // ---- column max: tree reduce (depth ~6) + cross-half ----
        float t8[8];
        #pragma unroll
        for (int r = 0; r < 8; ++r)
            t8[r] = fmaxf(fmaxf(st0[r], st0[r + 8]), fmaxf(st1[r], st1[r + 8]));
        float ta = fmaxf(t8[0], t8[4]), tb = fmaxf(t8[1], t8[5]);
        float tc = fmaxf(t8[2], t8[6]), td = fmaxf(t8[3], t8[7]);
        float mx = fmaxf(fmaxf(ta, tb), fmaxf(tc, td));
        mx = fmaxf(mx, __shfl_xor(mx, 32));

        // ---- defer-max: rescale only when max grew by > 8 ----
        if (!__all(mx <= m_st + 8.0f)) {
            float m_new = fmaxf(m_st, mx);
            float alpha = __builtin_amdgcn_exp2f(m_st - m_new);
            l_st *= alpha;
            #pragma unroll
            for (int r = 0; r < 16; ++r) { ot[0][r] *= alpha; ot[1][r] *= alpha; }
            m_st = m_new;
        }

        // ---- P = exp2(S - m), packed to bf16 pairs in-register ----
        float s0 = 0.f, s1 = 0.f, s2 = 0.f, s3 = 0.f;
        unsigned cp0[8], cp1[8];
        #pragma unroll
        for (int t = 0; t < 8; ++t) {
            float pa = __builtin_amdgcn_exp2f(st0[2 * t]     - m_st);
            float pb = __builtin_amdgcn_exp2f(st0[2 * t + 1] - m_st);
            float pc = __builtin_amdgcn_exp2f(st1[2 * t]     - m_st);
            float pd = __builtin_amdgcn_exp2f(st1[2 * t + 1] - m_st);
            s0 += pa; s1 += pb; s2 += pc; s3 += pd;
            cp0[t] = pkbf(pa, pb);
            cp1[t] = pkbf(pc, pd);
        }
        float sum = (s0 + s1) + (s2 + s3);
        sum += __shfl_xor(sum, 32);
        l_st += sum;

        // ---- O^T += V^T * P^T (cross-half exchange via shfl_xor + select) ----
        #pragma unroll
        for (int cb = 0; cb < 2; ++cb) {
            #pragma unroll
            for (int kk = 0; kk < 2; ++kk) {
                unsigned c0 = cb ? cp1[4 * kk + 0] : cp0[4 * kk + 0];
                unsigned c1 = cb ? cp1[4 * kk + 1] : cp0[4 * kk + 1];
                unsigned c2 = cb ? cp1[4 * kk + 2] : cp0[4 * kk + 2];
                unsigned c3 = cb ? cp1[4 * kk + 3] : cp0[4 * kk + 3];
                unsigned e0 = __shfl_xor(c0, 32);
                unsigned e1 = __shfl_xor(c1, 32);
                unsigned e2 = __shfl_xor(c2, 32);
                unsigned e3 = __shfl_xor(c3, 32);
                union { unsigned uu[4]; bf16x8 v; } pu;
                pu.uu[0] = hi ? e2 : c0;
                pu.uu[1] = hi ? e3 : c1;
                pu.uu[2] = hi ? c2 : e0;
                pu.uu[3] = hi ? c3 : e1;
                #pragma unroll
                for (int df = 0; df < 2; ++df) {
                    bf16x8 vf = *reinterpret_cast<const bf16x8*>(
                        &u.kv.V[g][df * 32 + l31][cb * 32 + kk * 16 + hi * 8]);
                    ot[df] = __builtin_amdgcn_mfma_f32_32x32x16_bf16(vf, pu.v, ot[df], 0, 0, 0);
                }
            }
        }
    }

    // ---- combine halves via LDS, then epilogue ----
    __syncthreads();
    if (wid >= 4) {
        u.ex.ml[w][lane][0] = m_st;
        u.ex.ml[w][lane][1] = l_st;
        #pragma unroll
        for (int df = 0; df < 2; ++df)
            #pragma unroll
            for (int r = 0; r < 16; ++r)
                u.ex.ob[w][df * 16 + r][lane] = ot[df][r];
    }
    __syncthreads();
    if (wid < 4) {
        float m1 = u.ex.ml[w][lane][0];
        float l1 = u.ex.ml[w][lane][1];
        float mm = fmaxf(m_st, m1);
        float a0 = __builtin_amdgcn_exp2f(m_st - mm);
        float a1 = __builtin_amdgcn_exp2f(m1 - mm);
        float invl = 1.0f / (l_st * a0 + l1 * a1);

        int n = qblk * 128 + w * 32 + l31;
        unsigned short* orow = attnout + ((size_t)(b * SEQ + n)) * INNER + h * 64;
        #pragma unroll
        for (int df = 0; df < 2; ++df) {
            #pragma unroll
            for (int t = 0; t < 4; ++t) {
                float v0 = (ot[df][4 * t]     * a0 + u.ex.ob[w][df * 16 + 4 * t]    [lane] * a1) * invl;
                float v1 = (ot[df][4 * t + 1] * a0 + u.ex.ob[w][df * 16 + 4 * t + 1][lane] * a1) * invl;
                float v2 = (ot[df][4 * t + 2] * a0 + u.ex.ob[w][df * 16 + 4 * t + 2][lane] * a1) * invl;
                float v3 = (ot[df][4 * t + 3] * a0 + u.ex.ob[w][df * 16 + 4 * t + 3][lane] * a1) * invl;
                unsigned w0 = pkbf(v0, v1);
                unsigned w1 = pkbf(v2, v3);
                unsigned long long pk = (unsigned long long)w0 | ((unsigned long long)w1 << 32);
                *reinterpret_cast<unsigned long long*>(orow + df * 32 + t * 8 + hi * 4) = pk;
            }
        }
    }
}

extern "C" void kernel_launch(void* const* d_in, const int* in_sizes, int n_in,
                              void* d_out, int out_size, void* d_ws, size_t ws_size,
                              hipStream_t stream)
{
    const float* x      = (const float*)d_in[0];
    const float* w_qkv  = (const float*)d_in[1];
    const float* w_out  = (const float*)d_in[2];
    const float* b_out  = (const float*)d_in[3];
    const float* scale  = (const float*)d_in[4];
    float* out = (float*)d_out;
    char* ws = (char*)d_ws;

    unsigned short* xb    = (unsigned short*)(ws);                 // 12,582,912
    unsigned short* wqkvb = (unsigned short*)(ws + 12582912);      //  3,538,944
    unsigned short* woutb = (unsigned short*)(ws + 16121856);      //  1,179,648
    unsigned short* attnb = (unsigned short*)(ws + 17301504);      // 12,582,912
    unsigned short* qb    = (unsigned short*)(ws + 29884416);      // 12,582,912
    unsigned short* kb    = (unsigned short*)(ws + 42467328);      // 12,582,912
    unsigned short* vtb   = (unsigned short*)(ws + 55050240);      // 12,582,912
    unsigned short* qkvb  = (unsigned short*)(ws + 67633152);      // 37,748,736

    cast_f32_bf16<<<6144, 256, 0, stream>>>(x, xb, 6291456);
    cast_f32_bf16<<<1728, 256, 0, stream>>>(w_qkv, wqkvb, 1769472);
    cast_f32_bf16<<<576, 256, 0, stream>>>(w_out, woutb, 589824);

    gemm_bt_kernel<true><<<dim3(64, 18), 256, 0, stream>>>(xb, wqkvb, qkvb, nullptr, ROWS, NQKV, DIMX);

    normalize_kernel<<<2048, 256, 0, stream>>>(qkvb, scale, qb, kb);
    vtrans_kernel<<<dim3(BATCH * HEADS, SEQ / 64), 256, 0, stream>>>(qkvb, vtb);

    attn_kernel<<<dim3(SEQ / 128, BATCH * HEADS), 512, 0, stream>>>(qb, kb, vtb, attnb);

    gemm_bt_kernel<false><<<dim3(64, 6), 256, 0, stream>>>(attnb, woutb, out, b_out, ROWS, INNER, INNER);
}

// Round 5
// 375.209 us; speedup vs baseline: 1.5421x; 1.5421x over previous
//
#include <hip/hip_runtime.h>
#include <hip/hip_bf16.h>

// Problem constants (from reference)
#define DIMX   768
#define HEADS  12
#define DH     64
#define INNER  768
#define NQKV   2304
#define SEQ    4096
#define BATCH  2
#define ROWS   (BATCH*SEQ)   // 8192
#define EPSF   1e-8f
#define LOG2E  1.4426950408889634f

typedef __bf16 bf16x8 __attribute__((ext_vector_type(8)));
typedef float  f32x4  __attribute__((ext_vector_type(4)));
typedef float  f32x16 __attribute__((ext_vector_type(16)));

// RNE f32 -> bf16 (finite inputs only)
__device__ __forceinline__ unsigned short f2bf(float f) {
    unsigned int u = __float_as_uint(f);
    unsigned int r = ((u >> 16) & 1u) + 0x7FFFu;
    return (unsigned short)((u + r) >> 16);
}
__device__ __forceinline__ float bf2f(unsigned short u) {
    return __builtin_bit_cast(float, (unsigned)u << 16);
}
// pack two f32 into a u32 of 2 bf16 (lo = a, hi = b) via native casts
__device__ __forceinline__ unsigned pkbf(float a, float b) {
    unsigned short la = __builtin_bit_cast(unsigned short, (__bf16)a);
    unsigned short lb = __builtin_bit_cast(unsigned short, (__bf16)b);
    return (unsigned)la | ((unsigned)lb << 16);
}

__global__ __launch_bounds__(256) void cast_f32_bf16(
    const float* __restrict__ src, unsigned short* __restrict__ dst, int n)
{
    int i = (blockIdx.x * 256 + threadIdx.x) * 4;
    if (i + 3 < n) {
        float4 v = *reinterpret_cast<const float4*>(src + i);
        ushort4 o;
        o.x = f2bf(v.x); o.y = f2bf(v.y); o.z = f2bf(v.z); o.w = f2bf(v.w);
        *reinterpret_cast<ushort4*>(dst + i) = o;
    }
}

// C[M][N] = A[M][K] (bf16) * B[N][K]^T (bf16) (+ bias); out f32 or bf16.
template<bool BF16OUT>
__global__ __launch_bounds__(256) void gemm_bt_kernel(
    const unsigned short* __restrict__ A,
    const unsigned short* __restrict__ B,
    void* __restrict__ Cv,
    const float* __restrict__ bias,
    int M, int N, int K)
{
    __shared__ unsigned short shA[128][72];
    __shared__ unsigned short shB[128][72];

    const int bm0 = blockIdx.x * 128;
    const int bn0 = blockIdx.y * 128;
    const int tid = threadIdx.x;
    const int lane = tid & 63;
    const int wid  = tid >> 6;
    const int l15  = lane & 15;
    const int l4   = lane >> 4;
    const int wr   = wid >> 1;
    const int wc   = wid & 1;

    f32x4 acc[4][4];
    #pragma unroll
    for (int i = 0; i < 4; ++i)
        #pragma unroll
        for (int j = 0; j < 4; ++j)
            acc[i][j] = (f32x4){0.f, 0.f, 0.f, 0.f};

    const int nkt = K >> 6;
    for (int kt = 0; kt < nkt; ++kt) {
        const int k0 = kt << 6;
        __syncthreads();
        #pragma unroll
        for (int it = 0; it < 4; ++it) {
            int c = tid + it * 256;
            int row = c >> 3, colc = c & 7;
            *reinterpret_cast<uint4*>(&shA[row][colc * 8]) =
                *reinterpret_cast<const uint4*>(&A[(size_t)(bm0 + row) * K + k0 + colc * 8]);
            *reinterpret_cast<uint4*>(&shB[row][colc * 8]) =
                *reinterpret_cast<const uint4*>(&B[(size_t)(bn0 + row) * K + k0 + colc * 8]);
        }
        __syncthreads();
        #pragma unroll
        for (int ks = 0; ks < 2; ++ks) {
            bf16x8 af[4], bfr[4];
            #pragma unroll
            for (int mf = 0; mf < 4; ++mf)
                af[mf] = *reinterpret_cast<const bf16x8*>(&shA[wr * 64 + mf * 16 + l15][ks * 32 + l4 * 8]);
            #pragma unroll
            for (int nf = 0; nf < 4; ++nf)
                bfr[nf] = *reinterpret_cast<const bf16x8*>(&shB[wc * 64 + nf * 16 + l15][ks * 32 + l4 * 8]);
            #pragma unroll
            for (int mf = 0; mf < 4; ++mf)
                #pragma unroll
                for (int nf = 0; nf < 4; ++nf)
                    acc[mf][nf] = __builtin_amdgcn_mfma_f32_16x16x32_bf16(
                        af[mf], bfr[nf], acc[mf][nf], 0, 0, 0);
        }
    }

    #pragma unroll
    for (int mf = 0; mf < 4; ++mf) {
        #pragma unroll
        for (int nf = 0; nf < 4; ++nf) {
            int col = bn0 + wc * 64 + nf * 16 + l15;
            float badd = bias ? bias[col] : 0.f;
            #pragma unroll
            for (int r = 0; r < 4; ++r) {
                int row = bm0 + wr * 64 + mf * 16 + l4 * 4 + r;
                if constexpr (BF16OUT)
                    ((unsigned short*)Cv)[(size_t)row * N + col] = f2bf(acc[mf][nf][r] + badd);
                else
                    ((float*)Cv)[(size_t)row * N + col] = acc[mf][nf][r] + badd;
            }
        }
    }
}

// Cross-head L2 norm on bf16 qkv; Q scaled by log2e/scale[h]. q,k only.
__global__ __launch_bounds__(256) void normalize_kernel(
    const unsigned short* __restrict__ qkv,
    const float* __restrict__ scale,
    unsigned short* __restrict__ qo,
    unsigned short* __restrict__ ko)
{
    int t = blockIdx.x * 256 + threadIdx.x;
    int row = t >> 6;
    int d = t & 63;
    int b = row >> 12;
    int n = row & 4095;
    const unsigned short* base = qkv + (size_t)row * NQKV;

    float qv[12], kv[12];
    float sq = 0.f, sk = 0.f;
    #pragma unroll
    for (int h = 0; h < 12; ++h) {
        qv[h] = bf2f(base[h * 64 + d]);
        kv[h] = bf2f(base[768 + h * 64 + d]);
        sq += qv[h] * qv[h];
        sk += kv[h] * kv[h];
    }
    float rq = rsqrtf(sqrtf(sq) + EPSF);
    float rk = rsqrtf(sqrtf(sk) + EPSF);
    #pragma unroll
    for (int h = 0; h < 12; ++h) {
        size_t bh = (size_t)(b * 12 + h);
        float fold = LOG2E / scale[h];
        qo[(bh * SEQ + n) * 64 + d] = f2bf(qv[h] * rq * fold);
        ko[(bh * SEQ + n) * 64 + d] = f2bf(kv[h] * rk);
    }
}

// V transpose: qkv bf16 v-part [b,n,h,d] -> vt [bh][d][n], coalesced both ways
// via a 64x64 LDS tile. Grid: (BATCH*HEADS, SEQ/64).
__global__ __launch_bounds__(256) void vtrans_kernel(
    const unsigned short* __restrict__ qkv,
    unsigned short* __restrict__ vt)
{
    __shared__ unsigned short tile[64][72];
    const int bh = blockIdx.x;
    const int nt = blockIdx.y;
    const int b = bh / HEADS, h = bh % HEADS;
    const int tid = threadIdx.x;

    #pragma unroll
    for (int it = 0; it < 2; ++it) {
        int c = tid + it * 256;
        int r = c >> 3, cc = c & 7;
        *reinterpret_cast<uint4*>(&tile[r][cc * 8]) =
            *reinterpret_cast<const uint4*>(
                &qkv[(size_t)(b * SEQ + nt * 64 + r) * NQKV + 1536 + h * 64 + cc * 8]);
    }
    __syncthreads();
    #pragma unroll
    for (int it = 0; it < 2; ++it) {
        int c = tid + it * 256;
        int d = c >> 3, nc = c & 7;
        ushort4 o0, o1;
        o0.x = tile[nc * 8 + 0][d]; o0.y = tile[nc * 8 + 1][d];
        o0.z = tile[nc * 8 + 2][d]; o0.w = tile[nc * 8 + 3][d];
        o1.x = tile[nc * 8 + 4][d]; o1.y = tile[nc * 8 + 5][d];
        o1.z = tile[nc * 8 + 6][d]; o1.w = tile[nc * 8 + 7][d];
        unsigned short* dst = &vt[((size_t)bh * 64 + d) * SEQ + nt * 64 + nc * 8];
        *reinterpret_cast<ushort4*>(dst)     = o0;
        *reinterpret_cast<ushort4*>(dst + 4) = o1;
    }
}

// Flash attention, 8 waves / 512 threads. Waves 0-3: kv [0,2048); waves 4-7:
// kv [2048,4096); same 128 q-rows. End-of-kernel (m,l,O^T) combine via LDS.
// NOTE: __launch_bounds__ 2nd arg is MIN WAVES PER EU (SIMD), not blocks/CU.
// (512,6) forced an 85-VGPR budget -> accumulator spill -> ~1 GB scratch
// traffic (round-4 counters). (512,2) caps at 256 VGPR; kernel needs ~110.
struct ShExch { float ob[4][32][64]; float ml[4][64][2]; };
struct ShKV   { unsigned short K[2][64][72]; unsigned short V[2][64][72]; };
union  ShU    { ShKV kv; ShExch ex; };

__global__ __launch_bounds__(512, 2) void attn_kernel(
    const unsigned short* __restrict__ qg,
    const unsigned short* __restrict__ kg,
    const unsigned short* __restrict__ vtg,
    unsigned short* __restrict__ attnout)
{
    __shared__ ShU u;

    const int qblk = blockIdx.x;
    const int bh   = blockIdx.y;
    const int b    = bh / HEADS;
    const int h    = bh % HEADS;
    const int tid  = threadIdx.x;
    const int lane = tid & 63;
    const int wid  = tid >> 6;     // 0..7
    const int w    = wid & 3;      // q-subtile
    const int g    = wid >> 2;     // kv half
    const int l31  = lane & 31;
    const int hi   = lane >> 5;
    const int tidg = tid & 255;

    // Q fragments (B operand, col=q=l31, k = d0*16 + hi*8 + j)
    bf16x8 qf[4];
    {
        const unsigned short* qrow =
            qg + ((size_t)bh * SEQ + qblk * 128 + w * 32 + l31) * 64 + hi * 8;
        #pragma unroll
        for (int d0 = 0; d0 < 4; ++d0)
            qf[d0] = *reinterpret_cast<const bf16x8*>(qrow + d0 * 16);
    }

    f32x16 ot[2];
    #pragma unroll
    for (int r = 0; r < 16; ++r) { ot[0][r] = 0.f; ot[1][r] = 0.f; }
    float m_st = -1e30f, l_st = 0.f;

    const unsigned short* kbase = kg  + ((size_t)bh * SEQ + g * 2048) * 64;
    const unsigned short* vbase = vtg + (size_t)bh * 64 * SEQ + g * 2048;

    for (int kt = 0; kt < 32; ++kt) {
        __syncthreads();
        #pragma unroll
        for (int it = 0; it < 2; ++it) {
            int c = tidg + it * 256;
            int row = c >> 3, colc = c & 7;
            *reinterpret_cast<uint4*>(&u.kv.K[g][row][colc * 8]) =
                *reinterpret_cast<const uint4*>(&kbase[(size_t)(kt * 64 + row) * 64 + colc * 8]);
            *reinterpret_cast<uint4*>(&u.kv.V[g][row][colc * 8]) =
                *reinterpret_cast<const uint4*>(&vbase[(size_t)row * SEQ + kt * 64 + colc * 8]);
        }
        __syncthreads();

        // ---- S^T = K * Q^T (exp2 domain: scale folded into Q) ----
        f32x16 st0, st1;
        #pragma unroll
        for (int r = 0; r < 16; ++r) { st0[r] = 0.f; st1[r] = 0.f; }
        #pragma unroll
        for (int d0 = 0; d0 < 4; ++d0) {
            bf16x8 kf0 = *reinterpret_cast<const bf16x8*>(&u.kv.K[g][l31][d0 * 16 + hi * 8]);
            bf16x8 kf1 = *reinterpret_cast<const bf16x8*>(&u.kv.K[g][32 + l31][d0 * 16 + hi * 8]);
            st0 = __builtin_amdgcn_mfma_f32_32x32x16_bf16(kf0, qf[d0], st0, 0, 0, 0);
            st1 = __builtin_amdgcn_mfma_f32_32x32x16_bf16(kf1, qf[d0], st1, 0, 0, 0);
        }

        // ---- column max: tree reduce (depth ~6) + cross-half ----
        float t8[8];
        #pragma unroll
        for (int r = 0; r < 8; ++r)
            t8[r] = fmaxf(fmaxf(st0[r], st0[r + 8]), fmaxf(st1[r], st1[r + 8]));
        float ta = fmaxf(t8[0], t8[4]), tb = fmaxf(t8[1], t8[5]);
        float tc = fmaxf(t8[2], t8[6]), td = fmaxf(t8[3], t8[7]);
        float mx = fmaxf(fmaxf(ta, tb), fmaxf(tc, td));
        mx = fmaxf(mx, __shfl_xor(mx, 32));

        // ---- defer-max: rescale only when max grew by > 8 ----
        if (!__all(mx <= m_st + 8.0f)) {
            float m_new = fmaxf(m_st, mx);
            float alpha = __builtin_amdgcn_exp2f(m_st - m_new);
            l_st *= alpha;
            #pragma unroll
            for (int r = 0; r < 16; ++r) { ot[0][r] *= alpha; ot[1][r] *= alpha; }
            m_st = m_new;
        }

        // ---- P = exp2(S - m), packed to bf16 pairs in-register ----
        float s0 = 0.f, s1 = 0.f, s2 = 0.f, s3 = 0.f;
        unsigned cp0[8], cp1[8];
        #pragma unroll
        for (int t = 0; t < 8; ++t) {
            float pa = __builtin_amdgcn_exp2f(st0[2 * t]     - m_st);
            float pb = __builtin_amdgcn_exp2f(st0[2 * t + 1] - m_st);
            float pc = __builtin_amdgcn_exp2f(st1[2 * t]     - m_st);
            float pd = __builtin_amdgcn_exp2f(st1[2 * t + 1] - m_st);
            s0 += pa; s1 += pb; s2 += pc; s3 += pd;
            cp0[t] = pkbf(pa, pb);
            cp1[t] = pkbf(pc, pd);
        }
        float sum = (s0 + s1) + (s2 + s3);
        sum += __shfl_xor(sum, 32);
        l_st += sum;

        // ---- O^T += V^T * P^T (cross-half exchange via shfl_xor + select) ----
        #pragma unroll
        for (int cb = 0; cb < 2; ++cb) {
            #pragma unroll
            for (int kk = 0; kk < 2; ++kk) {
                unsigned c0 = cb ? cp1[4 * kk + 0] : cp0[4 * kk + 0];
                unsigned c1 = cb ? cp1[4 * kk + 1] : cp0[4 * kk + 1];
                unsigned c2 = cb ? cp1[4 * kk + 2] : cp0[4 * kk + 2];
                unsigned c3 = cb ? cp1[4 * kk + 3] : cp0[4 * kk + 3];
                unsigned e0 = __shfl_xor(c0, 32);
                unsigned e1 = __shfl_xor(c1, 32);
                unsigned e2 = __shfl_xor(c2, 32);
                unsigned e3 = __shfl_xor(c3, 32);
                union { unsigned uu[4]; bf16x8 v; } pu;
                pu.uu[0] = hi ? e2 : c0;
                pu.uu[1] = hi ? e3 : c1;
                pu.uu[2] = hi ? c2 : e0;
                pu.uu[3] = hi ? c3 : e1;
                #pragma unroll
                for (int df = 0; df < 2; ++df) {
                    bf16x8 vf = *reinterpret_cast<const bf16x8*>(
                        &u.kv.V[g][df * 32 + l31][cb * 32 + kk * 16 + hi * 8]);
                    ot[df] = __builtin_amdgcn_mfma_f32_32x32x16_bf16(vf, pu.v, ot[df], 0, 0, 0);
                }
            }
        }
    }

    // ---- combine halves via LDS, then epilogue ----
    __syncthreads();
    if (wid >= 4) {
        u.ex.ml[w][lane][0] = m_st;
        u.ex.ml[w][lane][1] = l_st;
        #pragma unroll
        for (int df = 0; df < 2; ++df)
            #pragma unroll
            for (int r = 0; r < 16; ++r)
                u.ex.ob[w][df * 16 + r][lane] = ot[df][r];
    }
    __syncthreads();
    if (wid < 4) {
        float m1 = u.ex.ml[w][lane][0];
        float l1 = u.ex.ml[w][lane][1];
        float mm = fmaxf(m_st, m1);
        float a0 = __builtin_amdgcn_exp2f(m_st - mm);
        float a1 = __builtin_amdgcn_exp2f(m1 - mm);
        float invl = 1.0f / (l_st * a0 + l1 * a1);

        int n = qblk * 128 + w * 32 + l31;
        unsigned short* orow = attnout + ((size_t)(b * SEQ + n)) * INNER + h * 64;
        #pragma unroll
        for (int df = 0; df < 2; ++df) {
            #pragma unroll
            for (int t = 0; t < 4; ++t) {
                float v0 = (ot[df][4 * t]     * a0 + u.ex.ob[w][df * 16 + 4 * t]    [lane] * a1) * invl;
                float v1 = (ot[df][4 * t + 1] * a0 + u.ex.ob[w][df * 16 + 4 * t + 1][lane] * a1) * invl;
                float v2 = (ot[df][4 * t + 2] * a0 + u.ex.ob[w][df * 16 + 4 * t + 2][lane] * a1) * invl;
                float v3 = (ot[df][4 * t + 3] * a0 + u.ex.ob[w][df * 16 + 4 * t + 3][lane] * a1) * invl;
                unsigned w0 = pkbf(v0, v1);
                unsigned w1 = pkbf(v2, v3);
                unsigned long long pk = (unsigned long long)w0 | ((unsigned long long)w1 << 32);
                *reinterpret_cast<unsigned long long*>(orow + df * 32 + t * 8 + hi * 4) = pk;
            }
        }
    }
}

extern "C" void kernel_launch(void* const* d_in, const int* in_sizes, int n_in,
                              void* d_out, int out_size, void* d_ws, size_t ws_size,
                              hipStream_t stream)
{
    const float* x      = (const float*)d_in[0];
    const float* w_qkv  = (const float*)d_in[1];
    const float* w_out  = (const float*)d_in[2];
    const float* b_out  = (const float*)d_in[3];
    const float* scale  = (const float*)d_in[4];
    float* out = (float*)d_out;
    char* ws = (char*)d_ws;

    unsigned short* xb    = (unsigned short*)(ws);                 // 12,582,912
    unsigned short* wqkvb = (unsigned short*)(ws + 12582912);      //  3,538,944
    unsigned short* woutb = (unsigned short*)(ws + 16121856);      //  1,179,648
    unsigned short* attnb = (unsigned short*)(ws + 17301504);      // 12,582,912
    unsigned short* qb    = (unsigned short*)(ws + 29884416);      // 12,582,912
    unsigned short* kb    = (unsigned short*)(ws + 42467328);      // 12,582,912
    unsigned short* vtb   = (unsigned short*)(ws + 55050240);      // 12,582,912
    unsigned short* qkvb  = (unsigned short*)(ws + 67633152);      // 37,748,736

    cast_f32_bf16<<<6144, 256, 0, stream>>>(x, xb, 6291456);
    cast_f32_bf16<<<1728, 256, 0, stream>>>(w_qkv, wqkvb, 1769472);
    cast_f32_bf16<<<576, 256, 0, stream>>>(w_out, woutb, 589824);

    gemm_bt_kernel<true><<<dim3(64, 18), 256, 0, stream>>>(xb, wqkvb, qkvb, nullptr, ROWS, NQKV, DIMX);

    normalize_kernel<<<2048, 256, 0, stream>>>(qkvb, scale, qb, kb);
    vtrans_kernel<<<dim3(BATCH * HEADS, SEQ / 64), 256, 0, stream>>>(qkvb, vtb);

    attn_kernel<<<dim3(SEQ / 128, BATCH * HEADS), 512, 0, stream>>>(qb, kb, vtb, attnb);

    gemm_bt_kernel<false><<<dim3(64, 6), 256, 0, stream>>>(attnb, woutb, out, b_out, ROWS, INNER, INNER);
}

// Round 6
// 253.985 us; speedup vs baseline: 2.2781x; 1.4773x over previous
//
#include <hip/hip_runtime.h>
#include <hip/hip_bf16.h>

// Problem constants (from reference)
#define DIMX   768
#define HEADS  12
#define DH     64
#define INNER  768
#define NQKV   2304
#define SEQ    4096
#define BATCH  2
#define ROWS   (BATCH*SEQ)   // 8192
#define EPSF   1e-8f
#define LOG2E  1.4426950408889634f

typedef __bf16 bf16x8 __attribute__((ext_vector_type(8)));
typedef float  f32x4  __attribute__((ext_vector_type(4)));
typedef float  f32x16 __attribute__((ext_vector_type(16)));

// RNE f32 -> bf16 (finite inputs only)
__device__ __forceinline__ unsigned short f2bf(float f) {
    unsigned int u = __float_as_uint(f);
    unsigned int r = ((u >> 16) & 1u) + 0x7FFFu;
    return (unsigned short)((u + r) >> 16);
}
__device__ __forceinline__ float bf2f(unsigned short u) {
    return __builtin_bit_cast(float, (unsigned)u << 16);
}
// pack two f32 into a u32 of 2 bf16 (lo = a, hi = b) via native casts
__device__ __forceinline__ unsigned pkbf(float a, float b) {
    unsigned short la = __builtin_bit_cast(unsigned short, (__bf16)a);
    unsigned short lb = __builtin_bit_cast(unsigned short, (__bf16)b);
    return (unsigned)la | ((unsigned)lb << 16);
}

__global__ __launch_bounds__(256) void cast_f32_bf16(
    const float* __restrict__ src, unsigned short* __restrict__ dst, int n)
{
    int i = (blockIdx.x * 256 + threadIdx.x) * 4;
    if (i + 3 < n) {
        float4 v = *reinterpret_cast<const float4*>(src + i);
        ushort4 o;
        o.x = f2bf(v.x); o.y = f2bf(v.y); o.z = f2bf(v.z); o.w = f2bf(v.w);
        *reinterpret_cast<ushort4*>(dst + i) = o;
    }
}

// C[M][N] = A[M][K] (bf16) * B[N][K]^T (bf16) (+ bias); out f32 or bf16.
template<bool BF16OUT>
__global__ __launch_bounds__(256) void gemm_bt_kernel(
    const unsigned short* __restrict__ A,
    const unsigned short* __restrict__ B,
    void* __restrict__ Cv,
    const float* __restrict__ bias,
    int M, int N, int K)
{
    __shared__ unsigned short shA[128][72];
    __shared__ unsigned short shB[128][72];

    const int bm0 = blockIdx.x * 128;
    const int bn0 = blockIdx.y * 128;
    const int tid = threadIdx.x;
    const int lane = tid & 63;
    const int wid  = tid >> 6;
    const int l15  = lane & 15;
    const int l4   = lane >> 4;
    const int wr   = wid >> 1;
    const int wc   = wid & 1;

    f32x4 acc[4][4];
    #pragma unroll
    for (int i = 0; i < 4; ++i)
        #pragma unroll
        for (int j = 0; j < 4; ++j)
            acc[i][j] = (f32x4){0.f, 0.f, 0.f, 0.f};

    const int nkt = K >> 6;
    for (int kt = 0; kt < nkt; ++kt) {
        const int k0 = kt << 6;
        __syncthreads();
        #pragma unroll
        for (int it = 0; it < 4; ++it) {
            int c = tid + it * 256;
            int row = c >> 3, colc = c & 7;
            *reinterpret_cast<uint4*>(&shA[row][colc * 8]) =
                *reinterpret_cast<const uint4*>(&A[(size_t)(bm0 + row) * K + k0 + colc * 8]);
            *reinterpret_cast<uint4*>(&shB[row][colc * 8]) =
                *reinterpret_cast<const uint4*>(&B[(size_t)(bn0 + row) * K + k0 + colc * 8]);
        }
        __syncthreads();
        #pragma unroll
        for (int ks = 0; ks < 2; ++ks) {
            bf16x8 af[4], bfr[4];
            #pragma unroll
            for (int mf = 0; mf < 4; ++mf)
                af[mf] = *reinterpret_cast<const bf16x8*>(&shA[wr * 64 + mf * 16 + l15][ks * 32 + l4 * 8]);
            #pragma unroll
            for (int nf = 0; nf < 4; ++nf)
                bfr[nf] = *reinterpret_cast<const bf16x8*>(&shB[wc * 64 + nf * 16 + l15][ks * 32 + l4 * 8]);
            #pragma unroll
            for (int mf = 0; mf < 4; ++mf)
                #pragma unroll
                for (int nf = 0; nf < 4; ++nf)
                    acc[mf][nf] = __builtin_amdgcn_mfma_f32_16x16x32_bf16(
                        af[mf], bfr[nf], acc[mf][nf], 0, 0, 0);
        }
    }

    #pragma unroll
    for (int mf = 0; mf < 4; ++mf) {
        #pragma unroll
        for (int nf = 0; nf < 4; ++nf) {
            int col = bn0 + wc * 64 + nf * 16 + l15;
            float badd = bias ? bias[col] : 0.f;
            #pragma unroll
            for (int r = 0; r < 4; ++r) {
                int row = bm0 + wr * 64 + mf * 16 + l4 * 4 + r;
                if constexpr (BF16OUT)
                    ((unsigned short*)Cv)[(size_t)row * N + col] = f2bf(acc[mf][nf][r] + badd);
                else
                    ((float*)Cv)[(size_t)row * N + col] = acc[mf][nf][r] + badd;
            }
        }
    }
}

// Cross-head L2 norm on bf16 qkv; Q scaled by log2e/scale[h]. q,k only.
__global__ __launch_bounds__(256) void normalize_kernel(
    const unsigned short* __restrict__ qkv,
    const float* __restrict__ scale,
    unsigned short* __restrict__ qo,
    unsigned short* __restrict__ ko)
{
    int t = blockIdx.x * 256 + threadIdx.x;
    int row = t >> 6;
    int d = t & 63;
    int b = row >> 12;
    int n = row & 4095;
    const unsigned short* base = qkv + (size_t)row * NQKV;

    float qv[12], kv[12];
    float sq = 0.f, sk = 0.f;
    #pragma unroll
    for (int h = 0; h < 12; ++h) {
        qv[h] = bf2f(base[h * 64 + d]);
        kv[h] = bf2f(base[768 + h * 64 + d]);
        sq += qv[h] * qv[h];
        sk += kv[h] * kv[h];
    }
    float rq = rsqrtf(sqrtf(sq) + EPSF);
    float rk = rsqrtf(sqrtf(sk) + EPSF);
    #pragma unroll
    for (int h = 0; h < 12; ++h) {
        size_t bh = (size_t)(b * 12 + h);
        float fold = LOG2E / scale[h];
        qo[(bh * SEQ + n) * 64 + d] = f2bf(qv[h] * rq * fold);
        ko[(bh * SEQ + n) * 64 + d] = f2bf(kv[h] * rk);
    }
}

// V transpose: qkv bf16 v-part [b,n,h,d] -> vt [bh][d][n], coalesced both ways
// via a 64x64 LDS tile. Grid: (BATCH*HEADS, SEQ/64).
__global__ __launch_bounds__(256) void vtrans_kernel(
    const unsigned short* __restrict__ qkv,
    unsigned short* __restrict__ vt)
{
    __shared__ unsigned short tile[64][72];
    const int bh = blockIdx.x;
    const int nt = blockIdx.y;
    const int b = bh / HEADS, h = bh % HEADS;
    const int tid = threadIdx.x;

    #pragma unroll
    for (int it = 0; it < 2; ++it) {
        int c = tid + it * 256;
        int r = c >> 3, cc = c & 7;
        *reinterpret_cast<uint4*>(&tile[r][cc * 8]) =
            *reinterpret_cast<const uint4*>(
                &qkv[(size_t)(b * SEQ + nt * 64 + r) * NQKV + 1536 + h * 64 + cc * 8]);
    }
    __syncthreads();
    #pragma unroll
    for (int it = 0; it < 2; ++it) {
        int c = tid + it * 256;
        int d = c >> 3, nc = c & 7;
        ushort4 o0, o1;
        o0.x = tile[nc * 8 + 0][d]; o0.y = tile[nc * 8 + 1][d];
        o0.z = tile[nc * 8 + 2][d]; o0.w = tile[nc * 8 + 3][d];
        o1.x = tile[nc * 8 + 4][d]; o1.y = tile[nc * 8 + 5][d];
        o1.z = tile[nc * 8 + 6][d]; o1.w = tile[nc * 8 + 7][d];
        unsigned short* dst = &vt[((size_t)bh * 64 + d) * SEQ + nt * 64 + nc * 8];
        *reinterpret_cast<ushort4*>(dst)     = o0;
        *reinterpret_cast<ushort4*>(dst + 4) = o1;
    }
}

// Flash attention WITHOUT online max: cosine-sim scores are bounded
// (|s2| <~ 1.7 after the scale/log2e fold), and softmax is shift-invariant,
// so P = exp2(s2) directly; l accumulates lane-locally; single cross-half
// shfl at the end. 4 waves / 256 threads (round-3 structure: 0 LDS conflicts).
// S^T[kv][q] = mfma(Kfrag, Qfrag): q = lane&31 lane-local.
// O^T[d][q] = mfma(V^T frag, P^T frag): q = lane&31 again lane-local.
__global__ __launch_bounds__(256) void attn_kernel(
    const unsigned short* __restrict__ qg,
    const unsigned short* __restrict__ kg,
    const unsigned short* __restrict__ vtg,
    unsigned short* __restrict__ attnout)
{
    __shared__ unsigned short shK[64][72];   // [kv][d]
    __shared__ unsigned short shV[64][72];   // [d][kv]  (V^T)

    const int qblk = blockIdx.x;
    const int bh   = blockIdx.y;
    const int b    = bh / HEADS;
    const int h    = bh % HEADS;
    const int tid  = threadIdx.x;
    const int lane = tid & 63;
    const int wid  = tid >> 6;
    const int l31  = lane & 31;
    const int hi   = lane >> 5;

    // Q fragments (B operand, col=q=l31, k = d0*16 + hi*8 + j)
    bf16x8 qf[4];
    {
        const unsigned short* qrow =
            qg + ((size_t)bh * SEQ + qblk * 128 + wid * 32 + l31) * 64 + hi * 8;
        #pragma unroll
        for (int d0 = 0; d0 < 4; ++d0)
            qf[d0] = *reinterpret_cast<const bf16x8*>(qrow + d0 * 16);
    }

    f32x16 ot[2];
    #pragma unroll
    for (int r = 0; r < 16; ++r) { ot[0][r] = 0.f; ot[1][r] = 0.f; }
    float l_lane = 0.f;

    const unsigned short* kbase = kg  + (size_t)bh * SEQ * 64;
    const unsigned short* vbase = vtg + (size_t)bh * 64 * SEQ;

    for (int kt = 0; kt < SEQ / 64; ++kt) {
        __syncthreads();
        #pragma unroll
        for (int it = 0; it < 2; ++it) {
            int c = tid + it * 256;
            int row = c >> 3, colc = c & 7;
            *reinterpret_cast<uint4*>(&shK[row][colc * 8]) =
                *reinterpret_cast<const uint4*>(&kbase[(size_t)(kt * 64 + row) * 64 + colc * 8]);
            *reinterpret_cast<uint4*>(&shV[row][colc * 8]) =
                *reinterpret_cast<const uint4*>(&vbase[(size_t)row * SEQ + kt * 64 + colc * 8]);
        }
        __syncthreads();

        // ---- S^T = K * Q^T (exp2 domain: scale folded into Q) ----
        f32x16 st0, st1;
        #pragma unroll
        for (int r = 0; r < 16; ++r) { st0[r] = 0.f; st1[r] = 0.f; }
        #pragma unroll
        for (int d0 = 0; d0 < 4; ++d0) {
            bf16x8 kf0 = *reinterpret_cast<const bf16x8*>(&shK[l31][d0 * 16 + hi * 8]);
            bf16x8 kf1 = *reinterpret_cast<const bf16x8*>(&shK[32 + l31][d0 * 16 + hi * 8]);
            st0 = __builtin_amdgcn_mfma_f32_32x32x16_bf16(kf0, qf[d0], st0, 0, 0, 0);
            st1 = __builtin_amdgcn_mfma_f32_32x32x16_bf16(kf1, qf[d0], st1, 0, 0, 0);
        }

        // ---- P = exp2(S), no max shift (scores bounded); pack bf16 pairs ----
        float s0 = 0.f, s1 = 0.f, s2 = 0.f, s3 = 0.f;
        unsigned cp0[8], cp1[8];
        #pragma unroll
        for (int t = 0; t < 8; ++t) {
            float pa = __builtin_amdgcn_exp2f(st0[2 * t]);
            float pb = __builtin_amdgcn_exp2f(st0[2 * t + 1]);
            float pc = __builtin_amdgcn_exp2f(st1[2 * t]);
            float pd = __builtin_amdgcn_exp2f(st1[2 * t + 1]);
            s0 += pa; s1 += pb; s2 += pc; s3 += pd;
            cp0[t] = pkbf(pa, pb);
            cp1[t] = pkbf(pc, pd);
        }
        l_lane += (s0 + s1) + (s2 + s3);

        // ---- O^T += V^T * P^T (cross-half exchange via shfl_xor + select) ----
        #pragma unroll
        for (int cb = 0; cb < 2; ++cb) {
            #pragma unroll
            for (int kk = 0; kk < 2; ++kk) {
                unsigned c0 = cb ? cp1[4 * kk + 0] : cp0[4 * kk + 0];
                unsigned c1 = cb ? cp1[4 * kk + 1] : cp0[4 * kk + 1];
                unsigned c2 = cb ? cp1[4 * kk + 2] : cp0[4 * kk + 2];
                unsigned c3 = cb ? cp1[4 * kk + 3] : cp0[4 * kk + 3];
                unsigned e0 = __shfl_xor(c0, 32);
                unsigned e1 = __shfl_xor(c1, 32);
                unsigned e2 = __shfl_xor(c2, 32);
                unsigned e3 = __shfl_xor(c3, 32);
                union { unsigned uu[4]; bf16x8 v; } pu;
                pu.uu[0] = hi ? e2 : c0;
                pu.uu[1] = hi ? e3 : c1;
                pu.uu[2] = hi ? c2 : e0;
                pu.uu[3] = hi ? c3 : e1;
                #pragma unroll
                for (int df = 0; df < 2; ++df) {
                    bf16x8 vf = *reinterpret_cast<const bf16x8*>(
                        &shV[df * 32 + l31][cb * 32 + kk * 16 + hi * 8]);
                    ot[df] = __builtin_amdgcn_mfma_f32_32x32x16_bf16(vf, pu.v, ot[df], 0, 0, 0);
                }
            }
        }
    }

    // ---- epilogue: O[q][d] = O^T[d][q] / l, q = l31 lane-local ----
    float l_all = l_lane + __shfl_xor(l_lane, 32);
    float invl = 1.0f / l_all;
    int n = qblk * 128 + wid * 32 + l31;
    unsigned short* orow = attnout + ((size_t)(b * SEQ + n)) * INNER + h * 64;
    #pragma unroll
    for (int df = 0; df < 2; ++df) {
        #pragma unroll
        for (int t = 0; t < 4; ++t) {
            // regs 4t..4t+3 -> d = df*32 + t*8 + hi*4 + (0..3), contiguous quad
            unsigned w0 = pkbf(ot[df][4 * t]     * invl, ot[df][4 * t + 1] * invl);
            unsigned w1 = pkbf(ot[df][4 * t + 2] * invl, ot[df][4 * t + 3] * invl);
            unsigned long long pk = (unsigned long long)w0 | ((unsigned long long)w1 << 32);
            *reinterpret_cast<unsigned long long*>(orow + df * 32 + t * 8 + hi * 4) = pk;
        }
    }
}

extern "C" void kernel_launch(void* const* d_in, const int* in_sizes, int n_in,
                              void* d_out, int out_size, void* d_ws, size_t ws_size,
                              hipStream_t stream)
{
    const float* x      = (const float*)d_in[0];
    const float* w_qkv  = (const float*)d_in[1];
    const float* w_out  = (const float*)d_in[2];
    const float* b_out  = (const float*)d_in[3];
    const float* scale  = (const float*)d_in[4];
    float* out = (float*)d_out;
    char* ws = (char*)d_ws;

    unsigned short* xb    = (unsigned short*)(ws);                 // 12,582,912
    unsigned short* wqkvb = (unsigned short*)(ws + 12582912);      //  3,538,944
    unsigned short* woutb = (unsigned short*)(ws + 16121856);      //  1,179,648
    unsigned short* attnb = (unsigned short*)(ws + 17301504);      // 12,582,912
    unsigned short* qb    = (unsigned short*)(ws + 29884416);      // 12,582,912
    unsigned short* kb    = (unsigned short*)(ws + 42467328);      // 12,582,912
    unsigned short* vtb   = (unsigned short*)(ws + 55050240);      // 12,582,912
    unsigned short* qkvb  = (unsigned short*)(ws + 67633152);      // 37,748,736

    cast_f32_bf16<<<6144, 256, 0, stream>>>(x, xb, 6291456);
    cast_f32_bf16<<<1728, 256, 0, stream>>>(w_qkv, wqkvb, 1769472);
    cast_f32_bf16<<<576, 256, 0, stream>>>(w_out, woutb, 589824);

    gemm_bt_kernel<true><<<dim3(64, 18), 256, 0, stream>>>(xb, wqkvb, qkvb, nullptr, ROWS, NQKV, DIMX);

    normalize_kernel<<<2048, 256, 0, stream>>>(qkvb, scale, qb, kb);
    vtrans_kernel<<<dim3(BATCH * HEADS, SEQ / 64), 256, 0, stream>>>(qkvb, vtb);

    attn_kernel<<<dim3(SEQ / 128, BATCH * HEADS), 256, 0, stream>>>(qb, kb, vtb, attnb);

    gemm_bt_kernel<false><<<dim3(64, 6), 256, 0, stream>>>(attnb, woutb, out, b_out, ROWS, INNER, INNER);
}